// Round 4
// baseline (313.317 us; speedup 1.0000x reference)
//
#include <hip/hip_runtime.h>

typedef unsigned short ushort_t;
typedef unsigned int u32;
typedef unsigned long long u64;
typedef __attribute__((ext_vector_type(4))) float f32x4;
typedef __attribute__((ext_vector_type(16))) float f32x16;
typedef __attribute__((ext_vector_type(8))) short s16x8;

__device__ __forceinline__ ushort_t f2bf(float f) {
    u32 u = __float_as_uint(f);
    u32 r = u + 0x7fffu + ((u >> 16) & 1u);
    return (ushort_t)(r >> 16);
}
__device__ __forceinline__ u32 pk_trunc(float a, float b) {
    // truncating bf16 pair pack (P only; systematic -delta cancels in O/l)
    return (__float_as_uint(a) >> 16) | (__float_as_uint(b) & 0xffff0000u);
}
// async global->LDS, 16B/lane; LDS dest = wave-uniform base + lane*16.
__device__ __forceinline__ void cp16(const void* g, void* l) {
    __builtin_amdgcn_global_load_lds(
        (const __attribute__((address_space(1))) u32*)g,
        (__attribute__((address_space(3))) u32*)l, 16, 0, 0);
}

// ---------------- fp32 -> bf16 conversion ----------------
__global__ void cvt_qkv(const float* __restrict__ a, const float* __restrict__ b,
                        const float* __restrict__ c, ushort_t* __restrict__ oa,
                        ushort_t* __restrict__ ob, ushort_t* __restrict__ oc) {
    const float* s = blockIdx.y == 0 ? a : (blockIdx.y == 1 ? b : c);
    ushort_t* o = blockIdx.y == 0 ? oa : (blockIdx.y == 1 ? ob : oc);
    int i = (blockIdx.x * 256 + threadIdx.x) * 4;
    float4 v = *(const float4*)(s + i);
    u64 pk = (u64)f2bf(v.x) | ((u64)f2bf(v.y) << 16) |
             ((u64)f2bf(v.z) << 32) | ((u64)f2bf(v.w) << 48);
    *(u64*)(o + i) = pk;
}

__global__ void cvt_w(const float* __restrict__ a, const float* __restrict__ b,
                      const float* __restrict__ c, const float* __restrict__ d,
                      ushort_t* __restrict__ oa, ushort_t* __restrict__ ob,
                      ushort_t* __restrict__ oc, ushort_t* __restrict__ od) {
    const float* s; ushort_t* o;
    switch (blockIdx.y) {
        case 0: s = a; o = oa; break;
        case 1: s = b; o = ob; break;
        case 2: s = c; o = oc; break;
        default: s = d; o = od; break;
    }
    int i = (blockIdx.x * 256 + threadIdx.x) * 4;
    float4 v = *(const float4*)(s + i);
    u64 pk = (u64)f2bf(v.x) | ((u64)f2bf(v.y) << 16) |
             ((u64)f2bf(v.z) << 32) | ((u64)f2bf(v.w) << 48);
    *(u64*)(o + i) = pk;
}

// ---------------- mask -> per-lane 32x32-fragment-ordered bf16 bias ----------------
__global__ __launch_bounds__(256) void prep_mask(const int* __restrict__ m,
                                                 u32* __restrict__ mf) {
    __shared__ ushort_t ms[128 * 68];  // [q 128][k 64], +4 pad
    const int tid = threadIdx.x;
    const int kt = blockIdx.x, qt = blockIdx.y, b = blockIdx.z;
    const int* mg = m + ((size_t)(b * 2048 + qt * 128)) * 2048 + kt * 64;
#pragma unroll
    for (int rep = 0; rep < 8; rep++) {
        int linear = rep * 256 + tid;
        int row = linear >> 4, ci = linear & 15;
        int4 v = *(const int4*)(mg + (size_t)row * 2048 + ci * 4);
        u32 d0 = (v.x ? 0u : 0xC6EAu) | ((v.y ? 0u : 0xC6EAu) << 16);
        u32 d1 = (v.z ? 0u : 0xC6EAu) | ((v.w ? 0u : 0xC6EAu) << 16);
        *(uint2*)&ms[row * 68 + ci * 4] = make_uint2(d0, d1);
    }
    __syncthreads();
    const int w = tid >> 6, L = tid & 63, hf = L >> 5, q5 = L & 31;
    const int ql = w * 32 + q5;
    u32* out = mf + ((((size_t)b * 32 + kt) * 16 + qt) * 4 + w) * 1024 + L * 4;
    u32 vals[16];
#pragma unroll
    for (int mi = 0; mi < 16; mi++) {
        int mt = mi >> 3, r4 = (mi >> 1) & 3, bb = mi & 1;
        int kl = mt * 32 + r4 * 8 + hf * 4 + bb * 2;
        vals[mi] = *(const u32*)&ms[ql * 68 + kl];
    }
#pragma unroll
    for (int j = 0; j < 4; j++)
        *(uint4*)(out + j * 256) =
            make_uint4(vals[j * 4], vals[j * 4 + 1], vals[j * 4 + 2], vals[j * 4 + 3]);
}

// ---------------- fused q/k/v projection: 128x128 NT GEMM ----------------
// z=0: q scaled by 0.125*log2(e), [B,H,S,64]; z=1: k [B,H,S,64]
// z=2: vT = Wv x^T, stored [512][8192] (row = h*64+d, col = b*2048+s) -> coalesced stores
__global__ __launch_bounds__(256)
void gemm_qkv(const ushort_t* __restrict__ Aq, const ushort_t* __restrict__ Ak,
              const ushort_t* __restrict__ Av, const ushort_t* __restrict__ Wq,
              const ushort_t* __restrict__ Wk, const ushort_t* __restrict__ Wv,
              const float* __restrict__ bq, const float* __restrict__ bk,
              const float* __restrict__ bv, ushort_t* __restrict__ oq,
              ushort_t* __restrict__ ok, ushort_t* __restrict__ ov) {
    constexpr int K = 512;
    const int z = blockIdx.z;
    // z<2: A = activation (M=8192), B = weight (N=512). z=2: A = Wv (M=512), B = activation (N=8192).
    const ushort_t* A = z == 0 ? Aq : (z == 1 ? Ak : Wv);
    const ushort_t* Bm = z == 0 ? Wq : (z == 1 ? Wk : Av);
    const float* bias = z == 0 ? bq : (z == 1 ? bk : bv);
    ushort_t* out = z == 0 ? oq : (z == 1 ? ok : ov);
    const float scale = z == 0 ? 0.18033688f : 1.0f;  // 0.125*log2(e)
    const int bm = (z == 2) ? blockIdx.y : blockIdx.x;
    const int bn = (z == 2) ? blockIdx.x : blockIdx.y;

    __shared__ ushort_t As[128 * 32];
    __shared__ ushort_t Bs[128 * 32];
    const int tid = threadIdx.x;
    const int wave = tid >> 6, lane = tid & 63, quad = lane >> 4, l16 = lane & 15;
    const int wm = (wave >> 1) * 64, wn = (wave & 1) * 64;

    const ushort_t* Ag = A + (size_t)(bm * 128 + (tid >> 2)) * K + (tid & 3) * 8;
    const ushort_t* Bg = Bm + (size_t)(bn * 128 + (tid >> 2)) * K + (tid & 3) * 8;

    f32x4 acc[4][4];
#pragma unroll
    for (int i = 0; i < 4; i++)
#pragma unroll
        for (int j = 0; j < 4; j++) acc[i][j] = (f32x4){0.f, 0.f, 0.f, 0.f};

    for (int kt = 0; kt < K; kt += 32) {
        __syncthreads();
        cp16(Ag + kt, (char*)As + tid * 16);
        cp16(Ag + 64 * K + kt, (char*)As + 4096 + tid * 16);
        cp16(Bg + kt, (char*)Bs + tid * 16);
        cp16(Bg + 64 * K + kt, (char*)Bs + 4096 + tid * 16);
        __syncthreads();
        s16x8 af[4], bf[4];
#pragma unroll
        for (int i = 0; i < 4; i++)
            af[i] = *(const s16x8*)&As[(wm + i * 16 + l16) * 32 + quad * 8];
#pragma unroll
        for (int j = 0; j < 4; j++)
            bf[j] = *(const s16x8*)&Bs[(wn + j * 16 + l16) * 32 + quad * 8];
#pragma unroll
        for (int i = 0; i < 4; i++)
#pragma unroll
            for (int j = 0; j < 4; j++)
                acc[i][j] = __builtin_amdgcn_mfma_f32_16x16x32_bf16(af[i], bf[j], acc[i][j], 0, 0, 0);
    }

    if (z == 2) {
        // C[row=Wv out-chan][col=b*2048+s], bias indexed by row; store [512][8192]
#pragma unroll
        for (int i = 0; i < 4; i++) {
            const int gm0 = bm * 128 + wm + i * 16 + quad * 4;
            const float4 b4 = *(const float4*)&bias[gm0];
#pragma unroll
            for (int j = 0; j < 4; j++) {
                const int gn = bn * 128 + wn + j * 16 + l16;
                out[(size_t)(gm0 + 0) * 8192 + gn] = f2bf(acc[i][j][0] + b4.x);
                out[(size_t)(gm0 + 1) * 8192 + gn] = f2bf(acc[i][j][1] + b4.y);
                out[(size_t)(gm0 + 2) * 8192 + gn] = f2bf(acc[i][j][2] + b4.z);
                out[(size_t)(gm0 + 3) * 8192 + gn] = f2bf(acc[i][j][3] + b4.w);
            }
        }
    } else {
#pragma unroll
        for (int j = 0; j < 4; j++) {
            const int gn = bn * 128 + wn + j * 16 + l16;
            const float bb = bias[gn];
            const int hh = gn >> 6, dd = gn & 63;
#pragma unroll
            for (int i = 0; i < 4; i++) {
                const int gm0 = bm * 128 + wm + i * 16 + quad * 4;
                const int bi = gm0 >> 11, s0 = gm0 & 2047;
#pragma unroll
                for (int p = 0; p < 4; p++)
                    out[(((size_t)(bi * 8 + hh)) * 2048 + s0 + p) * 64 + dd] =
                        f2bf((acc[i][j][p] + bb) * scale);
            }
        }
    }
}

// ---------------- output projection: 128x64 tile, fp32 out ----------------
__global__ __launch_bounds__(256)
void gemm_out(const ushort_t* __restrict__ A, const ushort_t* __restrict__ W,
              const float* __restrict__ bias, float* __restrict__ out) {
    __shared__ ushort_t As[128 * 32];
    __shared__ ushort_t Bs[64 * 32];
    const int tid = threadIdx.x, bm = blockIdx.x, bn = blockIdx.y;
    const int wave = tid >> 6, lane = tid & 63, quad = lane >> 4, l16 = lane & 15;
    const ushort_t* Ag = A + (size_t)(bm * 128 + (tid >> 2)) * 512 + (tid & 3) * 8;
    const ushort_t* Bg = W + (size_t)(bn * 64 + (tid >> 2)) * 512 + (tid & 3) * 8;

    f32x4 acc[2][4];
#pragma unroll
    for (int i = 0; i < 2; i++)
#pragma unroll
        for (int j = 0; j < 4; j++) acc[i][j] = (f32x4){0.f, 0.f, 0.f, 0.f};

    for (int kt = 0; kt < 512; kt += 32) {
        __syncthreads();
        cp16(Ag + kt, (char*)As + tid * 16);
        cp16(Ag + 64 * 512 + kt, (char*)As + 4096 + tid * 16);
        cp16(Bg + kt, (char*)Bs + tid * 16);
        __syncthreads();
        s16x8 af[2], bf[4];
#pragma unroll
        for (int i = 0; i < 2; i++)
            af[i] = *(const s16x8*)&As[(wave * 32 + i * 16 + l16) * 32 + quad * 8];
#pragma unroll
        for (int j = 0; j < 4; j++)
            bf[j] = *(const s16x8*)&Bs[(j * 16 + l16) * 32 + quad * 8];
#pragma unroll
        for (int i = 0; i < 2; i++)
#pragma unroll
            for (int j = 0; j < 4; j++)
                acc[i][j] = __builtin_amdgcn_mfma_f32_16x16x32_bf16(af[i], bf[j], acc[i][j], 0, 0, 0);
    }

#pragma unroll
    for (int j = 0; j < 4; j++) {
        const int gn = bn * 64 + j * 16 + l16;
        const float bb = bias[gn];
#pragma unroll
        for (int i = 0; i < 2; i++) {
            const int gm0 = bm * 128 + wave * 32 + i * 16 + quad * 4;
#pragma unroll
            for (int p = 0; p < 4; p++)
                out[(size_t)(gm0 + p) * 512 + gn] = acc[i][j][p] + bb;
        }
    }
}

// ---------------- fused attention: 32x32 MFMA, fixed-max softmax, SPLIT-K ----------------
// grid (16 qt128, 8 h, 4b*2ks), 256 thr. Wave owns 32 q (q = lane&31).
// Each block does 1024 k-positions; partials are exactly additive (no running max).
// Writes partial O (fp32, [ks][b][s][512]) and partial l ([ks][b][h][s]).
__global__ __launch_bounds__(256, 4)
void attn(const ushort_t* __restrict__ q, const ushort_t* __restrict__ k,
          const ushort_t* __restrict__ vT, const u32* __restrict__ mf,
          float* __restrict__ po, float* __restrict__ pl) {
    __shared__ ushort_t Ks[2][64 * 64];  // double-buffered K tile, XOR chunk-swizzled

    const int tid = threadIdx.x;
    const int qt = blockIdx.x, hh = blockIdx.y;
    const int b = blockIdx.z >> 1, ks = blockIdx.z & 1;
    const int w = tid >> 6, L = tid & 63, hf = L >> 5, q5 = L & 31;
    const size_t bh = (size_t)b * 8 + hh;
    const ushort_t* qg = q + (bh * 2048 + qt * 128 + w * 32) * 64;
    const ushort_t* kg = k + bh * 2048 * 64 + (size_t)ks * 65536;
    // vT [512][8192]: row = hh*64 + d, col = b*2048 + kpos
    const ushort_t* vg = vT + ((size_t)hh * 64 + q5) * 8192 + b * 2048 + ks * 1024;
    const u32* mg = mf + ((((size_t)b * 32 + ks * 16) * 16 + qt) * 4 + w) * 1024 + L * 4;

    const int lin0 = tid, lin1 = 256 + tid;
    const int sr0 = lin0 >> 3, sc0 = lin0 & 7;
    const int sr1 = lin1 >> 3, sc1 = lin1 & 7;
    const size_t goff0 = (size_t)sr0 * 64 + (size_t)((sc0 ^ (sr0 & 7)) * 8);
    const size_t goff1 = (size_t)sr1 * 64 + (size_t)((sc1 ^ (sr1 & 7)) * 8);

    cp16(kg + goff0, (char*)Ks[0] + lin0 * 16);
    cp16(kg + goff1, (char*)Ks[0] + lin1 * 16);

    s16x8 Qf[4];
#pragma unroll
    for (int s = 0; s < 4; s++)
        Qf[s] = *(const s16x8*)(qg + q5 * 64 + s * 16 + hf * 8);

    union { u32 u[4]; s16x8 v; } ou;
    ou.u[0] = ou.u[1] = ou.u[2] = ou.u[3] = 0x3F803F80u;
    const s16x8 onesf = ou.v;

    f32x16 O0, O1, lacc;
#pragma unroll
    for (int i = 0; i < 16; i++) { O0[i] = 0.f; O1[i] = 0.f; lacc[i] = 0.f; }

    for (int it = 0; it < 16; ++it) {
        const int cur = it & 1;
        __syncthreads();  // K[cur] staged
        if (it + 1 < 16) {
            const ushort_t* kn = kg + (size_t)(it + 1) * 4096;
            cp16(kn + goff0, (char*)Ks[1 - cur] + lin0 * 16);
            cp16(kn + goff1, (char*)Ks[1 - cur] + lin1 * 16);
        }

        uint4 mj[4];
#pragma unroll
        for (int j = 0; j < 4; j++)
            mj[j] = *(const uint4*)(mg + (size_t)it * 65536 + j * 256);

        s16x8 Vf[2][4];
#pragma unroll
        for (int mt = 0; mt < 2; mt++)
#pragma unroll
            for (int s = 0; s < 4; s++)
                Vf[mt][s] = *(const s16x8*)(vg + (size_t)mt * 32 * 8192 + it * 64 + s * 16 + hf * 8);

        f32x16 c0, c1;
#pragma unroll
        for (int i = 0; i < 16; i++) { c0[i] = 0.f; c1[i] = 0.f; }
#pragma unroll
        for (int s = 0; s < 4; s++) {
            const s16x8 kf0 = *(const s16x8*)&Ks[cur][q5 * 64 + (((2 * s + hf) ^ (q5 & 7)) * 8)];
            c0 = __builtin_amdgcn_mfma_f32_32x32x16_bf16(kf0, Qf[s], c0, 0, 0, 0);
        }
#pragma unroll
        for (int s = 0; s < 4; s++) {
            const s16x8 kf1 = *(const s16x8*)&Ks[cur][(32 + q5) * 64 + (((2 * s + hf) ^ (q5 & 7)) * 8)];
            c1 = __builtin_amdgcn_mfma_f32_32x32x16_bf16(kf1, Qf[s], c1, 0, 0, 0);
        }

        u32 P[16];
#pragma unroll
        for (int mi = 0; mi < 16; mi++) {
            const int reg = ((mi >> 1) & 3) * 4 + (mi & 1) * 2;
            const u32 mw = (mi & 3) == 0 ? mj[mi >> 2].x
                         : (mi & 3) == 1 ? mj[mi >> 2].y
                         : (mi & 3) == 2 ? mj[mi >> 2].z : mj[mi >> 2].w;
            const float b0 = __uint_as_float(mw << 16);
            const float b1 = __uint_as_float(mw & 0xffff0000u);
            const float s0 = (mi < 8) ? c0[reg] : c1[reg];
            const float s1 = (mi < 8) ? c0[reg + 1] : c1[reg + 1];
            const float e0 = __builtin_amdgcn_exp2f(s0 + b0);
            const float e1 = __builtin_amdgcn_exp2f(s1 + b1);
            P[mi] = pk_trunc(e0, e1);
        }

#pragma unroll
        for (int s = 0; s < 4; s++) {
            const u32 a0 = P[4 * s], a1 = P[4 * s + 1];
            const u32 b0 = P[4 * s + 2], b1 = P[4 * s + 3];
            const u32 send0 = hf ? a0 : b0;
            const u32 send1 = hf ? a1 : b1;
            const u32 r0 = __shfl_xor((int)send0, 32);
            const u32 r1 = __shfl_xor((int)send1, 32);
            union { uint4 u; s16x8 v; } pu;
            pu.u.x = hf ? r0 : a0;
            pu.u.y = hf ? r1 : a1;
            pu.u.z = hf ? b0 : r0;
            pu.u.w = hf ? b1 : r1;
            const s16x8 Pf = pu.v;
            O0 = __builtin_amdgcn_mfma_f32_32x32x16_bf16(Vf[0][s], Pf, O0, 0, 0, 0);
            O1 = __builtin_amdgcn_mfma_f32_32x32x16_bf16(Vf[1][s], Pf, O1, 0, 0, 0);
            lacc = __builtin_amdgcn_mfma_f32_32x32x16_bf16(onesf, Pf, lacc, 0, 0, 0);
        }
    }

    const int qrow = qt * 128 + w * 32 + q5;
    if (hf == 0)
        pl[(((size_t)ks * 4 + b) * 8 + hh) * 2048 + qrow] = lacc[0];
    float* por = po + (((size_t)ks * 4 + b) * 2048 + qrow) * 512 + hh * 64;
#pragma unroll
    for (int mt = 0; mt < 2; mt++)
#pragma unroll
        for (int r4 = 0; r4 < 4; r4++) {
            const int d = mt * 32 + r4 * 8 + hf * 4;
            float4 v;
            v.x = mt ? O1[r4 * 4 + 0] : O0[r4 * 4 + 0];
            v.y = mt ? O1[r4 * 4 + 1] : O0[r4 * 4 + 1];
            v.z = mt ? O1[r4 * 4 + 2] : O0[r4 * 4 + 2];
            v.w = mt ? O1[r4 * 4 + 3] : O0[r4 * 4 + 3];
            *(float4*)(por + d) = v;
        }
}

// ---------------- combine split-K partials -> bf16 x ----------------
__global__ __launch_bounds__(256)
void combine(const float* __restrict__ po, const float* __restrict__ pl,
             ushort_t* __restrict__ x) {
    const size_t i = ((size_t)blockIdx.x * 256 + threadIdx.x) * 8;
    const size_t row = i >> 9;          // b*2048 + s
    const int c = (int)(i & 511), h = c >> 6;
    const int b = (int)(row >> 11);
    const int s = (int)(row & 2047);
    const float l0 = pl[(((size_t)b) * 8 + h) * 2048 + s];
    const float l1 = pl[(((size_t)4 + b) * 8 + h) * 2048 + s];
    const float inv = 1.0f / (l0 + l1);
    const float* p0 = po + row * 512 + c;
    const float* p1 = p0 + (size_t)4 * 2048 * 512;
    float4 a0 = *(const float4*)p0, a1 = *(const float4*)(p0 + 4);
    float4 b0 = *(const float4*)p1, b1 = *(const float4*)(p1 + 4);
    u32 o0 = (u32)f2bf((a0.x + b0.x) * inv) | ((u32)f2bf((a0.y + b0.y) * inv) << 16);
    u32 o1 = (u32)f2bf((a0.z + b0.z) * inv) | ((u32)f2bf((a0.w + b0.w) * inv) << 16);
    u32 o2 = (u32)f2bf((a1.x + b1.x) * inv) | ((u32)f2bf((a1.y + b1.y) * inv) << 16);
    u32 o3 = (u32)f2bf((a1.z + b1.z) * inv) | ((u32)f2bf((a1.w + b1.w) * inv) << 16);
    *(uint4*)(x + i) = make_uint4(o0, o1, o2, o3);
}

// ---------------- launch ----------------
extern "C" void kernel_launch(void* const* d_in, const int* in_sizes, int n_in,
                              void* d_out, int out_size, void* d_ws, size_t ws_size,
                              hipStream_t stream) {
    const float* query = (const float*)d_in[0];
    const float* key_ = (const float*)d_in[1];
    const float* value = (const float*)d_in[2];
    const int* mask = (const int*)d_in[3];
    const float* Wq = (const float*)d_in[4];
    const float* bq = (const float*)d_in[5];
    const float* Wk = (const float*)d_in[6];
    const float* bk = (const float*)d_in[7];
    const float* Wv = (const float*)d_in[8];
    const float* bv = (const float*)d_in[9];
    const float* Wo = (const float*)d_in[10];
    const float* bo = (const float*)d_in[11];

    const size_t E = 4194304;  // 8192*512
    const size_t W = 262144;   // 512*512
    ushort_t* qb = (ushort_t*)d_ws;
    ushort_t* kb = qb + E;
    ushort_t* vb = kb + E;
    ushort_t* Wqb = vb + E;
    ushort_t* Wkb = Wqb + W;
    ushort_t* Wvb = Wkb + W;
    ushort_t* Wob = Wvb + W;
    ushort_t* mfb = Wob + W;  // 16.78M ushorts
    ushort_t* qp = mfb + (size_t)4 * 2048 * 2048;
    ushort_t* kp = qp + E;
    ushort_t* vTp = kp + E;   // [512][8192]
    ushort_t* xp = vTp + E;
    float* po = (float*)(xp + E);            // 2*4*2048*512 fp32 = 33.5 MB
    float* pl = po + (size_t)2 * 4 * 2048 * 512;  // 2*4*8*2048 fp32

    cvt_qkv<<<dim3(4096, 3), 256, 0, stream>>>(query, key_, value, qb, kb, vb);
    cvt_w<<<dim3(256, 4), 256, 0, stream>>>(Wq, Wk, Wv, Wo, Wqb, Wkb, Wvb, Wob);
    prep_mask<<<dim3(32, 16, 4), 256, 0, stream>>>(mask, (u32*)mfb);

    gemm_qkv<<<dim3(64, 4, 3), 256, 0, stream>>>(qb, kb, vb, Wqb, Wkb, Wvb,
                                                 bq, bk, bv, qp, kp, vTp);

    attn<<<dim3(16, 8, 8), 256, 0, stream>>>(qp, kp, vTp, (const u32*)mfb, po, pl);

    combine<<<dim3(2048), 256, 0, stream>>>(po, pl, xp);

    gemm_out<<<dim3(64, 8), 256, 0, stream>>>(xp, Wob, bo, (float*)d_out);
}

// Round 5
// 297.163 us; speedup vs baseline: 1.0544x; 1.0544x over previous
//
#include <hip/hip_runtime.h>

typedef unsigned short ushort_t;
typedef unsigned int u32;
typedef unsigned long long u64;
typedef __attribute__((ext_vector_type(4))) float f32x4;
typedef __attribute__((ext_vector_type(16))) float f32x16;
typedef __attribute__((ext_vector_type(8))) short s16x8;

__device__ __forceinline__ ushort_t f2bf(float f) {
    u32 u = __float_as_uint(f);
    u32 r = u + 0x7fffu + ((u >> 16) & 1u);
    return (ushort_t)(r >> 16);
}
__device__ __forceinline__ u32 pk_trunc(float a, float b) {
    // truncating bf16 pair pack (P only; systematic -delta cancels in O/l)
    return (__float_as_uint(a) >> 16) | (__float_as_uint(b) & 0xffff0000u);
}
// async global->LDS, 16B/lane; LDS dest = wave-uniform base + lane*16.
__device__ __forceinline__ void cp16(const void* g, void* l) {
    __builtin_amdgcn_global_load_lds(
        (const __attribute__((address_space(1))) u32*)g,
        (__attribute__((address_space(3))) u32*)l, 16, 0, 0);
}

// ---------------- fp32 -> bf16 conversion ----------------
__global__ void cvt_qkv(const float* __restrict__ a, const float* __restrict__ b,
                        const float* __restrict__ c, ushort_t* __restrict__ oa,
                        ushort_t* __restrict__ ob, ushort_t* __restrict__ oc) {
    const float* s = blockIdx.y == 0 ? a : (blockIdx.y == 1 ? b : c);
    ushort_t* o = blockIdx.y == 0 ? oa : (blockIdx.y == 1 ? ob : oc);
    int i = (blockIdx.x * 256 + threadIdx.x) * 4;
    float4 v = *(const float4*)(s + i);
    u64 pk = (u64)f2bf(v.x) | ((u64)f2bf(v.y) << 16) |
             ((u64)f2bf(v.z) << 32) | ((u64)f2bf(v.w) << 48);
    *(u64*)(o + i) = pk;
}

__global__ void cvt_w(const float* __restrict__ a, const float* __restrict__ b,
                      const float* __restrict__ c, const float* __restrict__ d,
                      ushort_t* __restrict__ oa, ushort_t* __restrict__ ob,
                      ushort_t* __restrict__ oc, ushort_t* __restrict__ od) {
    const float* s; ushort_t* o;
    switch (blockIdx.y) {
        case 0: s = a; o = oa; break;
        case 1: s = b; o = ob; break;
        case 2: s = c; o = oc; break;
        default: s = d; o = od; break;
    }
    int i = (blockIdx.x * 256 + threadIdx.x) * 4;
    float4 v = *(const float4*)(s + i);
    u64 pk = (u64)f2bf(v.x) | ((u64)f2bf(v.y) << 16) |
             ((u64)f2bf(v.z) << 32) | ((u64)f2bf(v.w) << 48);
    *(u64*)(o + i) = pk;
}

// ---------------- mask -> per-lane 32x32-fragment-ordered bf16 bias ----------------
__global__ __launch_bounds__(256) void prep_mask(const int* __restrict__ m,
                                                 u32* __restrict__ mf) {
    __shared__ ushort_t ms[128 * 68];  // [q 128][k 64], +4 pad
    const int tid = threadIdx.x;
    const int kt = blockIdx.x, qt = blockIdx.y, b = blockIdx.z;
    const int* mg = m + ((size_t)(b * 2048 + qt * 128)) * 2048 + kt * 64;
#pragma unroll
    for (int rep = 0; rep < 8; rep++) {
        int linear = rep * 256 + tid;
        int row = linear >> 4, ci = linear & 15;
        int4 v = *(const int4*)(mg + (size_t)row * 2048 + ci * 4);
        u32 d0 = (v.x ? 0u : 0xC6EAu) | ((v.y ? 0u : 0xC6EAu) << 16);
        u32 d1 = (v.z ? 0u : 0xC6EAu) | ((v.w ? 0u : 0xC6EAu) << 16);
        *(uint2*)&ms[row * 68 + ci * 4] = make_uint2(d0, d1);
    }
    __syncthreads();
    const int w = tid >> 6, L = tid & 63, hf = L >> 5, q5 = L & 31;
    const int ql = w * 32 + q5;
    u32* out = mf + ((((size_t)b * 32 + kt) * 16 + qt) * 4 + w) * 1024 + L * 4;
    u32 vals[16];
#pragma unroll
    for (int mi = 0; mi < 16; mi++) {
        int mt = mi >> 3, r4 = (mi >> 1) & 3, bb = mi & 1;
        int kl = mt * 32 + r4 * 8 + hf * 4 + bb * 2;
        vals[mi] = *(const u32*)&ms[ql * 68 + kl];
    }
#pragma unroll
    for (int j = 0; j < 4; j++)
        *(uint4*)(out + j * 256) =
            make_uint4(vals[j * 4], vals[j * 4 + 1], vals[j * 4 + 2], vals[j * 4 + 3]);
}

// ---------------- fused q/k/v projection: 128x128 NT GEMM ----------------
// z=0: q scaled by 0.125*log2(e), [B,H,S,64]; z=1: k [B,H,S,64]
// z=2: vT = Wv x^T, stored [512][8192] (row = h*64+d, col = b*2048+s) -> coalesced stores
__global__ __launch_bounds__(256)
void gemm_qkv(const ushort_t* __restrict__ Aq, const ushort_t* __restrict__ Ak,
              const ushort_t* __restrict__ Av, const ushort_t* __restrict__ Wq,
              const ushort_t* __restrict__ Wk, const ushort_t* __restrict__ Wv,
              const float* __restrict__ bq, const float* __restrict__ bk,
              const float* __restrict__ bv, ushort_t* __restrict__ oq,
              ushort_t* __restrict__ ok, ushort_t* __restrict__ ov) {
    constexpr int K = 512;
    const int z = blockIdx.z;
    const ushort_t* A = z == 0 ? Aq : (z == 1 ? Ak : Wv);
    const ushort_t* Bm = z == 0 ? Wq : (z == 1 ? Wk : Av);
    const float* bias = z == 0 ? bq : (z == 1 ? bk : bv);
    ushort_t* out = z == 0 ? oq : (z == 1 ? ok : ov);
    const float scale = z == 0 ? 0.18033688f : 1.0f;  // 0.125*log2(e)
    const int bm = (z == 2) ? blockIdx.y : blockIdx.x;
    const int bn = (z == 2) ? blockIdx.x : blockIdx.y;

    __shared__ ushort_t As[128 * 32];
    __shared__ ushort_t Bs[128 * 32];
    const int tid = threadIdx.x;
    const int wave = tid >> 6, lane = tid & 63, quad = lane >> 4, l16 = lane & 15;
    const int wm = (wave >> 1) * 64, wn = (wave & 1) * 64;

    const ushort_t* Ag = A + (size_t)(bm * 128 + (tid >> 2)) * K + (tid & 3) * 8;
    const ushort_t* Bg = Bm + (size_t)(bn * 128 + (tid >> 2)) * K + (tid & 3) * 8;

    f32x4 acc[4][4];
#pragma unroll
    for (int i = 0; i < 4; i++)
#pragma unroll
        for (int j = 0; j < 4; j++) acc[i][j] = (f32x4){0.f, 0.f, 0.f, 0.f};

    for (int kt = 0; kt < K; kt += 32) {
        __syncthreads();
        cp16(Ag + kt, (char*)As + tid * 16);
        cp16(Ag + 64 * K + kt, (char*)As + 4096 + tid * 16);
        cp16(Bg + kt, (char*)Bs + tid * 16);
        cp16(Bg + 64 * K + kt, (char*)Bs + 4096 + tid * 16);
        __syncthreads();
        s16x8 af[4], bf[4];
#pragma unroll
        for (int i = 0; i < 4; i++)
            af[i] = *(const s16x8*)&As[(wm + i * 16 + l16) * 32 + quad * 8];
#pragma unroll
        for (int j = 0; j < 4; j++)
            bf[j] = *(const s16x8*)&Bs[(wn + j * 16 + l16) * 32 + quad * 8];
#pragma unroll
        for (int i = 0; i < 4; i++)
#pragma unroll
            for (int j = 0; j < 4; j++)
                acc[i][j] = __builtin_amdgcn_mfma_f32_16x16x32_bf16(af[i], bf[j], acc[i][j], 0, 0, 0);
    }

    if (z == 2) {
#pragma unroll
        for (int i = 0; i < 4; i++) {
            const int gm0 = bm * 128 + wm + i * 16 + quad * 4;
            const float4 b4 = *(const float4*)&bias[gm0];
#pragma unroll
            for (int j = 0; j < 4; j++) {
                const int gn = bn * 128 + wn + j * 16 + l16;
                out[(size_t)(gm0 + 0) * 8192 + gn] = f2bf(acc[i][j][0] + b4.x);
                out[(size_t)(gm0 + 1) * 8192 + gn] = f2bf(acc[i][j][1] + b4.y);
                out[(size_t)(gm0 + 2) * 8192 + gn] = f2bf(acc[i][j][2] + b4.z);
                out[(size_t)(gm0 + 3) * 8192 + gn] = f2bf(acc[i][j][3] + b4.w);
            }
        }
    } else {
#pragma unroll
        for (int j = 0; j < 4; j++) {
            const int gn = bn * 128 + wn + j * 16 + l16;
            const float bb = bias[gn];
            const int hh = gn >> 6, dd = gn & 63;
#pragma unroll
            for (int i = 0; i < 4; i++) {
                const int gm0 = bm * 128 + wm + i * 16 + quad * 4;
                const int bi = gm0 >> 11, s0 = gm0 & 2047;
#pragma unroll
                for (int p = 0; p < 4; p++)
                    out[(((size_t)(bi * 8 + hh)) * 2048 + s0 + p) * 64 + dd] =
                        f2bf((acc[i][j][p] + bb) * scale);
            }
        }
    }
}

// ---------------- output projection: 128x64 tile, fp32 out ----------------
__global__ __launch_bounds__(256)
void gemm_out(const ushort_t* __restrict__ A, const ushort_t* __restrict__ W,
              const float* __restrict__ bias, float* __restrict__ out) {
    __shared__ ushort_t As[128 * 32];
    __shared__ ushort_t Bs[64 * 32];
    const int tid = threadIdx.x, bm = blockIdx.x, bn = blockIdx.y;
    const int wave = tid >> 6, lane = tid & 63, quad = lane >> 4, l16 = lane & 15;
    const ushort_t* Ag = A + (size_t)(bm * 128 + (tid >> 2)) * 512 + (tid & 3) * 8;
    const ushort_t* Bg = W + (size_t)(bn * 64 + (tid >> 2)) * 512 + (tid & 3) * 8;

    f32x4 acc[2][4];
#pragma unroll
    for (int i = 0; i < 2; i++)
#pragma unroll
        for (int j = 0; j < 4; j++) acc[i][j] = (f32x4){0.f, 0.f, 0.f, 0.f};

    for (int kt = 0; kt < 512; kt += 32) {
        __syncthreads();
        cp16(Ag + kt, (char*)As + tid * 16);
        cp16(Ag + 64 * 512 + kt, (char*)As + 4096 + tid * 16);
        cp16(Bg + kt, (char*)Bs + tid * 16);
        __syncthreads();
        s16x8 af[2], bf[4];
#pragma unroll
        for (int i = 0; i < 2; i++)
            af[i] = *(const s16x8*)&As[(wave * 32 + i * 16 + l16) * 32 + quad * 8];
#pragma unroll
        for (int j = 0; j < 4; j++)
            bf[j] = *(const s16x8*)&Bs[(j * 16 + l16) * 32 + quad * 8];
#pragma unroll
        for (int i = 0; i < 2; i++)
#pragma unroll
            for (int j = 0; j < 4; j++)
                acc[i][j] = __builtin_amdgcn_mfma_f32_16x16x32_bf16(af[i], bf[j], acc[i][j], 0, 0, 0);
    }

#pragma unroll
    for (int j = 0; j < 4; j++) {
        const int gn = bn * 64 + j * 16 + l16;
        const float bb = bias[gn];
#pragma unroll
        for (int i = 0; i < 2; i++) {
            const int gm0 = bm * 128 + wave * 32 + i * 16 + quad * 4;
#pragma unroll
            for (int p = 0; p < 4; p++)
                out[(size_t)(gm0 + p) * 512 + gn] = acc[i][j][p] + bb;
        }
    }
}

// ---------------- fused attention: 32x32 MFMA, fixed-max softmax, SPLIT-K ----------------
// grid (16 qt128, 8 h, 4b*2ks), 256 thr. Wave owns 32 q (q = lane&31).
// V now staged via cp16->LDS (coalesced), fragments via swizzled ds_read_b128 —
// fixes the 32-cache-lines-per-instruction V loads of r3/r4.
__global__ __launch_bounds__(256, 4)
void attn(const ushort_t* __restrict__ q, const ushort_t* __restrict__ k,
          const ushort_t* __restrict__ vT, const u32* __restrict__ mf,
          float* __restrict__ po, float* __restrict__ pl) {
    __shared__ ushort_t Ks[2][64 * 64];  // double-buffered, XOR chunk-swizzled
    __shared__ ushort_t Vs[2][64 * 64];  // double-buffered, XOR chunk-swizzled

    const int tid = threadIdx.x;
    const int qt = blockIdx.x, hh = blockIdx.y;
    const int b = blockIdx.z >> 1, ks = blockIdx.z & 1;
    const int w = tid >> 6, L = tid & 63, hf = L >> 5, q5 = L & 31;
    const size_t bh = (size_t)b * 8 + hh;
    const ushort_t* qg = q + (bh * 2048 + qt * 128 + w * 32) * 64;
    const ushort_t* kg = k + bh * 2048 * 64 + (size_t)ks * 65536;
    // vT [512][8192]: row = hh*64 + d, col = b*2048 + kpos
    const ushort_t* vg = vT + (size_t)hh * 64 * 8192 + b * 2048 + ks * 1024;
    const u32* mg = mf + ((((size_t)b * 32 + ks * 16) * 16 + qt) * 4 + w) * 1024 + L * 4;

    // staging maps (per-thread constant): LDS chunk (sr,sc) <- global chunk (sr, sc^(sr&7))
    const int lin0 = tid, lin1 = 256 + tid;
    const int sr0 = lin0 >> 3, sc0 = lin0 & 7;
    const int sr1 = lin1 >> 3, sc1 = lin1 & 7;
    const size_t kgo0 = (size_t)sr0 * 64 + (size_t)((sc0 ^ (sr0 & 7)) * 8);
    const size_t kgo1 = (size_t)sr1 * 64 + (size_t)((sc1 ^ (sr1 & 7)) * 8);
    const size_t vgo0 = (size_t)sr0 * 8192 + (size_t)((sc0 ^ (sr0 & 7)) * 8);
    const size_t vgo1 = (size_t)sr1 * 8192 + (size_t)((sc1 ^ (sr1 & 7)) * 8);

    cp16(kg + kgo0, (char*)Ks[0] + lin0 * 16);
    cp16(kg + kgo1, (char*)Ks[0] + lin1 * 16);
    cp16(vg + vgo0, (char*)Vs[0] + lin0 * 16);
    cp16(vg + vgo1, (char*)Vs[0] + lin1 * 16);

    s16x8 Qf[4];
#pragma unroll
    for (int s = 0; s < 4; s++)
        Qf[s] = *(const s16x8*)(qg + q5 * 64 + s * 16 + hf * 8);

    union { u32 u[4]; s16x8 v; } ou;
    ou.u[0] = ou.u[1] = ou.u[2] = ou.u[3] = 0x3F803F80u;
    const s16x8 onesf = ou.v;

    f32x16 O0, O1, lacc;
#pragma unroll
    for (int i = 0; i < 16; i++) { O0[i] = 0.f; O1[i] = 0.f; lacc[i] = 0.f; }

    for (int it = 0; it < 16; ++it) {
        const int cur = it & 1;
        __syncthreads();  // K/V[cur] staged
        if (it + 1 < 16) {
            const ushort_t* kn = kg + (size_t)(it + 1) * 4096;
            const ushort_t* vn = vg + (size_t)(it + 1) * 64;
            cp16(kn + kgo0, (char*)Ks[1 - cur] + lin0 * 16);
            cp16(kn + kgo1, (char*)Ks[1 - cur] + lin1 * 16);
            cp16(vn + vgo0, (char*)Vs[1 - cur] + lin0 * 16);
            cp16(vn + vgo1, (char*)Vs[1 - cur] + lin1 * 16);
        }

        uint4 mj[4];
#pragma unroll
        for (int j = 0; j < 4; j++)
            mj[j] = *(const uint4*)(mg + (size_t)it * 65536 + j * 256);

        f32x16 c0, c1;
#pragma unroll
        for (int i = 0; i < 16; i++) { c0[i] = 0.f; c1[i] = 0.f; }
#pragma unroll
        for (int s = 0; s < 4; s++) {
            const s16x8 kf0 = *(const s16x8*)&Ks[cur][q5 * 64 + (((2 * s + hf) ^ (q5 & 7)) * 8)];
            c0 = __builtin_amdgcn_mfma_f32_32x32x16_bf16(kf0, Qf[s], c0, 0, 0, 0);
        }
#pragma unroll
        for (int s = 0; s < 4; s++) {
            const s16x8 kf1 = *(const s16x8*)&Ks[cur][(32 + q5) * 64 + (((2 * s + hf) ^ (q5 & 7)) * 8)];
            c1 = __builtin_amdgcn_mfma_f32_32x32x16_bf16(kf1, Qf[s], c1, 0, 0, 0);
        }

        u32 P[16];
#pragma unroll
        for (int mi = 0; mi < 16; mi++) {
            const int reg = ((mi >> 1) & 3) * 4 + (mi & 1) * 2;
            const u32 mw = (mi & 3) == 0 ? mj[mi >> 2].x
                         : (mi & 3) == 1 ? mj[mi >> 2].y
                         : (mi & 3) == 2 ? mj[mi >> 2].z : mj[mi >> 2].w;
            const float b0 = __uint_as_float(mw << 16);
            const float b1 = __uint_as_float(mw & 0xffff0000u);
            const float s0 = (mi < 8) ? c0[reg] : c1[reg];
            const float s1 = (mi < 8) ? c0[reg + 1] : c1[reg + 1];
            const float e0 = __builtin_amdgcn_exp2f(s0 + b0);
            const float e1 = __builtin_amdgcn_exp2f(s1 + b1);
            P[mi] = pk_trunc(e0, e1);
        }

        // V A-frags from LDS: row = mt*32 + q5, chunk = (2s+hf)^(q5&7)
#pragma unroll
        for (int s = 0; s < 4; s++) {
            const u32 a0 = P[4 * s], a1 = P[4 * s + 1];
            const u32 b0 = P[4 * s + 2], b1 = P[4 * s + 3];
            const u32 send0 = hf ? a0 : b0;
            const u32 send1 = hf ? a1 : b1;
            const u32 r0 = __shfl_xor((int)send0, 32);
            const u32 r1 = __shfl_xor((int)send1, 32);
            union { uint4 u; s16x8 v; } pu;
            pu.u.x = hf ? r0 : a0;
            pu.u.y = hf ? r1 : a1;
            pu.u.z = hf ? b0 : r0;
            pu.u.w = hf ? b1 : r1;
            const s16x8 Pf = pu.v;
            const s16x8 vf0 = *(const s16x8*)&Vs[cur][q5 * 64 + (((2 * s + hf) ^ (q5 & 7)) * 8)];
            const s16x8 vf1 = *(const s16x8*)&Vs[cur][(32 + q5) * 64 + (((2 * s + hf) ^ (q5 & 7)) * 8)];
            O0 = __builtin_amdgcn_mfma_f32_32x32x16_bf16(vf0, Pf, O0, 0, 0, 0);
            O1 = __builtin_amdgcn_mfma_f32_32x32x16_bf16(vf1, Pf, O1, 0, 0, 0);
            lacc = __builtin_amdgcn_mfma_f32_32x32x16_bf16(onesf, Pf, lacc, 0, 0, 0);
        }
    }

    const int qrow = qt * 128 + w * 32 + q5;
    if (hf == 0)
        pl[(((size_t)ks * 4 + b) * 8 + hh) * 2048 + qrow] = lacc[0];
    float* por = po + (((size_t)ks * 4 + b) * 2048 + qrow) * 512 + hh * 64;
#pragma unroll
    for (int mt = 0; mt < 2; mt++)
#pragma unroll
        for (int r4 = 0; r4 < 4; r4++) {
            const int d = mt * 32 + r4 * 8 + hf * 4;
            float4 v;
            v.x = mt ? O1[r4 * 4 + 0] : O0[r4 * 4 + 0];
            v.y = mt ? O1[r4 * 4 + 1] : O0[r4 * 4 + 1];
            v.z = mt ? O1[r4 * 4 + 2] : O0[r4 * 4 + 2];
            v.w = mt ? O1[r4 * 4 + 3] : O0[r4 * 4 + 3];
            *(float4*)(por + d) = v;
        }
}

// ---------------- combine split-K partials -> bf16 x ----------------
__global__ __launch_bounds__(256)
void combine(const float* __restrict__ po, const float* __restrict__ pl,
             ushort_t* __restrict__ x) {
    const size_t i = ((size_t)blockIdx.x * 256 + threadIdx.x) * 8;
    const size_t row = i >> 9;          // b*2048 + s
    const int c = (int)(i & 511), h = c >> 6;
    const int b = (int)(row >> 11);
    const int s = (int)(row & 2047);
    const float l0 = pl[(((size_t)b) * 8 + h) * 2048 + s];
    const float l1 = pl[(((size_t)4 + b) * 8 + h) * 2048 + s];
    const float inv = 1.0f / (l0 + l1);
    const float* p0 = po + row * 512 + c;
    const float* p1 = p0 + (size_t)4 * 2048 * 512;
    float4 a0 = *(const float4*)p0, a1 = *(const float4*)(p0 + 4);
    float4 b0 = *(const float4*)p1, b1 = *(const float4*)(p1 + 4);
    u32 o0 = (u32)f2bf((a0.x + b0.x) * inv) | ((u32)f2bf((a0.y + b0.y) * inv) << 16);
    u32 o1 = (u32)f2bf((a0.z + b0.z) * inv) | ((u32)f2bf((a0.w + b0.w) * inv) << 16);
    u32 o2 = (u32)f2bf((a1.x + b1.x) * inv) | ((u32)f2bf((a1.y + b1.y) * inv) << 16);
    u32 o3 = (u32)f2bf((a1.z + b1.z) * inv) | ((u32)f2bf((a1.w + b1.w) * inv) << 16);
    *(uint4*)(x + i) = make_uint4(o0, o1, o2, o3);
}

// ---------------- launch ----------------
extern "C" void kernel_launch(void* const* d_in, const int* in_sizes, int n_in,
                              void* d_out, int out_size, void* d_ws, size_t ws_size,
                              hipStream_t stream) {
    const float* query = (const float*)d_in[0];
    const float* key_ = (const float*)d_in[1];
    const float* value = (const float*)d_in[2];
    const int* mask = (const int*)d_in[3];
    const float* Wq = (const float*)d_in[4];
    const float* bq = (const float*)d_in[5];
    const float* Wk = (const float*)d_in[6];
    const float* bk = (const float*)d_in[7];
    const float* Wv = (const float*)d_in[8];
    const float* bv = (const float*)d_in[9];
    const float* Wo = (const float*)d_in[10];
    const float* bo = (const float*)d_in[11];

    const size_t E = 4194304;  // 8192*512
    const size_t W = 262144;   // 512*512
    ushort_t* qb = (ushort_t*)d_ws;
    ushort_t* kb = qb + E;
    ushort_t* vb = kb + E;
    ushort_t* Wqb = vb + E;
    ushort_t* Wkb = Wqb + W;
    ushort_t* Wvb = Wkb + W;
    ushort_t* Wob = Wvb + W;
    ushort_t* mfb = Wob + W;  // 16.78M ushorts
    ushort_t* qp = mfb + (size_t)4 * 2048 * 2048;
    ushort_t* kp = qp + E;
    ushort_t* vTp = kp + E;   // [512][8192]
    ushort_t* xp = vTp + E;
    float* po = (float*)(xp + E);            // 2*4*2048*512 fp32 = 33.5 MB
    float* pl = po + (size_t)2 * 4 * 2048 * 512;  // 2*4*8*2048 fp32

    cvt_qkv<<<dim3(4096, 3), 256, 0, stream>>>(query, key_, value, qb, kb, vb);
    cvt_w<<<dim3(256, 4), 256, 0, stream>>>(Wq, Wk, Wv, Wo, Wqb, Wkb, Wvb, Wob);
    prep_mask<<<dim3(32, 16, 4), 256, 0, stream>>>(mask, (u32*)mfb);

    gemm_qkv<<<dim3(64, 4, 3), 256, 0, stream>>>(qb, kb, vb, Wqb, Wkb, Wvb,
                                                 bq, bk, bv, qp, kp, vTp);

    attn<<<dim3(16, 8, 8), 256, 0, stream>>>(qp, kp, vTp, (const u32*)mfb, po, pl);

    combine<<<dim3(2048), 256, 0, stream>>>(po, pl, xp);

    gemm_out<<<dim3(64, 8), 256, 0, stream>>>(xp, Wob, bo, (float*)d_out);
}